// Round 1
// baseline (4075.755 us; speedup 1.0000x reference)
//
#include <hip/hip_runtime.h>
#include <math.h>

#define NN 50000
#define NE 400000
#define NG 256
#define FIN 79
#define DD 400
#define BN_EPS_F 1e-5f

// ---------------- elementwise: z = (1+eps)*h ----------------
__global__ void k_init_z(const float* __restrict__ h, float* __restrict__ z,
                         const float* __restrict__ eps, int total) {
    float s = 1.0f + eps[0];
    int i = blockIdx.x * blockDim.x + threadIdx.x;
    int stride = gridDim.x * blockDim.x;
    for (; i < total; i += stride) z[i] = s * h[i];
}

// ---------------- edge scatter: z[dst] += h[src] ----------------
__global__ void k_edge_scatter(const float* __restrict__ h, float* __restrict__ z,
                               const int* __restrict__ src, const int* __restrict__ dst,
                               int F) {
    int e = blockIdx.x;
    int s = src[e];
    int d = dst[e];
    const float* hs = h + (size_t)s * F;
    float* zd = z + (size_t)d * F;
    for (int c = threadIdx.x; c < F; c += blockDim.x)
        atomicAdd(zd + c, hs[c]);
}

// ---------------- fused GEMM: Y = epilogue(A @ W + bias) ----------------
// A: [M,K] row-major, W: [K,Nc] row-major, Y: [M,Nc]
// mode 0: BN(inference) + relu ; mode 1: relu ; mode 2: tanh
__global__ __launch_bounds__(256)
void k_gemm_fused(const float* __restrict__ A, const float* __restrict__ W,
                  const float* __restrict__ bias,
                  const float* __restrict__ bng, const float* __restrict__ bnb,
                  const float* __restrict__ bnm, const float* __restrict__ bnv,
                  float* __restrict__ Y, int M, int K, int Nc, int mode)
{
    __shared__ float As[16][68];  // As[k][m], 64+4 pad
    __shared__ float Bs[16][68];  // Bs[k][n]

    int tid = threadIdx.x;
    int tx = tid & 15;        // 0..15 -> output cols (4 each)
    int ty = tid >> 4;        // 0..15 -> output rows (4 each)
    int m0 = blockIdx.x * 64;
    int n0 = blockIdx.y * 64;

    int acol = tid & 15;      // A tile col (k)
    int arow = tid >> 4;      // A tile row base (0..15)
    int bcol = tid & 63;      // B tile col (n)
    int brow = tid >> 6;      // B tile row base (0..3)

    float acc[4][4] = {{0.0f}};

    int ktiles = (K + 15) >> 4;
    for (int kt = 0; kt < ktiles; ++kt) {
        int k0 = kt << 4;
        #pragma unroll
        for (int i = 0; i < 4; ++i) {
            int r = arow + (i << 4);            // 0..63
            int gr = m0 + r, gc = k0 + acol;
            As[acol][r] = (gr < M && gc < K) ? A[(size_t)gr * K + gc] : 0.0f;
        }
        #pragma unroll
        for (int i = 0; i < 4; ++i) {
            int r = brow + (i << 2);            // 0..15
            int gr = k0 + r, gc = n0 + bcol;
            Bs[r][bcol] = (gr < K && gc < Nc) ? W[(size_t)gr * Nc + gc] : 0.0f;
        }
        __syncthreads();
        #pragma unroll
        for (int kk = 0; kk < 16; ++kk) {
            float4 a4 = *(const float4*)&As[kk][ty << 2];
            float4 b4 = *(const float4*)&Bs[kk][tx << 2];
            float a[4] = {a4.x, a4.y, a4.z, a4.w};
            float b[4] = {b4.x, b4.y, b4.z, b4.w};
            #pragma unroll
            for (int i = 0; i < 4; ++i)
                #pragma unroll
                for (int j = 0; j < 4; ++j)
                    acc[i][j] += a[i] * b[j];
        }
        __syncthreads();
    }

    #pragma unroll
    for (int j = 0; j < 4; ++j) {
        int c = n0 + (tx << 2) + j;
        if (c >= Nc) continue;
        float bias_c = bias[c];
        float sc = 1.0f, sh = 0.0f;
        if (mode == 0) {
            sc = bng[c] * rsqrtf(bnv[c] + BN_EPS_F);
            sh = bnb[c] - bnm[c] * sc;
        }
        #pragma unroll
        for (int i = 0; i < 4; ++i) {
            int r = m0 + (ty << 2) + i;
            if (r >= M) continue;
            float val = acc[i][j] + bias_c;
            if (mode == 0)      { val = fmaxf(val * sc + sh, 0.0f); }
            else if (mode == 1) { val = fmaxf(val, 0.0f); }
            else                { val = tanhf(val); }
            Y[(size_t)r * Nc + c] = val;
        }
    }
}

// ---------------- per-graph start offsets via binary search ----------------
__global__ void k_gstart(const int* __restrict__ batch, int* __restrict__ gstart) {
    int g = blockIdx.x * blockDim.x + threadIdx.x;
    if (g > NG) return;
    int lo = 0, hi = NN;
    while (lo < hi) {
        int mid = (lo + hi) >> 1;
        if (batch[mid] < g) lo = mid + 1; else hi = mid;
    }
    gstart[g] = lo;
}

// ---------------- pooling: max + mean per graph ----------------
__global__ void k_pool(const float* __restrict__ t, const int* __restrict__ gstart,
                       float* __restrict__ pooled) {
    int g = blockIdx.x;
    int c = blockIdx.y * blockDim.x + threadIdx.x;
    if (c >= DD) return;
    int s = gstart[g], e = gstart[g + 1];
    float mx = -INFINITY, sm = 0.0f;
    for (int n = s; n < e; ++n) {
        float v = t[(size_t)n * DD + c];
        mx = fmaxf(mx, v);
        sm += v;
    }
    float cnt = (float)(e - s);
    pooled[(size_t)g * 2 * DD + c] = mx;
    pooled[(size_t)g * 2 * DD + DD + c] = sm / fmaxf(cnt, 1.0f);
}

// ---------------- final: out[g] = pooled[g,:] . w + b ----------------
__global__ void k_final(const float* __restrict__ pooled, const float* __restrict__ w,
                        const float* __restrict__ b, float* __restrict__ out) {
    __shared__ float red[256];
    int g = blockIdx.x;
    float p = 0.0f;
    for (int j = threadIdx.x; j < 2 * DD; j += blockDim.x)
        p += pooled[(size_t)g * 2 * DD + j] * w[j];
    red[threadIdx.x] = p;
    __syncthreads();
    for (int s = 128; s > 0; s >>= 1) {
        if (threadIdx.x < s) red[threadIdx.x] += red[threadIdx.x + s];
        __syncthreads();
    }
    if (threadIdx.x == 0) out[g] = red[0] + b[0];
}

extern "C" void kernel_launch(void* const* d_in, const int* in_sizes, int n_in,
                              void* d_out, int out_size, void* d_ws, size_t ws_size,
                              hipStream_t stream) {
    const float* x     = (const float*)d_in[0];
    const int*   ei    = (const int*)d_in[1];
    const int*   batch = (const int*)d_in[2];
    const float* m1w1  = (const float*)d_in[4];
    const float* m1b1  = (const float*)d_in[5];
    const float* m1g   = (const float*)d_in[6];
    const float* m1bb  = (const float*)d_in[7];
    const float* m1m   = (const float*)d_in[8];
    const float* m1v   = (const float*)d_in[9];
    const float* m1w2  = (const float*)d_in[10];
    const float* m1b2  = (const float*)d_in[11];
    const float* m2w1  = (const float*)d_in[12];
    const float* m2b1  = (const float*)d_in[13];
    const float* m2g   = (const float*)d_in[14];
    const float* m2bb  = (const float*)d_in[15];
    const float* m2m   = (const float*)d_in[16];
    const float* m2v   = (const float*)d_in[17];
    const float* m2w2  = (const float*)d_in[18];
    const float* m2b2  = (const float*)d_in[19];
    const float* o1w   = (const float*)d_in[20];
    const float* o1b   = (const float*)d_in[21];
    const float* o2w   = (const float*)d_in[22];
    const float* o2b   = (const float*)d_in[23];
    const float* o3w   = (const float*)d_in[24];
    const float* o3b   = (const float*)d_in[25];
    const float* ow    = (const float*)d_in[26];
    const float* ob    = (const float*)d_in[27];
    const float* eps1  = (const float*)d_in[28];
    const float* eps2  = (const float*)d_in[29];
    const float* eps3  = (const float*)d_in[30];
    const int* srcI = ei;
    const int* dstI = ei + NE;

    float* bufA   = (float*)d_ws;                      // NN*DD
    float* bufB   = bufA + (size_t)NN * DD;            // NN*DD
    float* z0     = bufB + (size_t)NN * DD;            // NN*FIN
    float* pooled = z0 + (size_t)NN * FIN;             // NG*2*DD
    int*   gstart = (int*)(pooled + (size_t)NG * 2 * DD); // NG+1

    float* out = (float*)d_out;

    dim3 gemmGrid((NN + 63) / 64, (DD + 63) / 64);

    k_gstart<<<2, 256, 0, stream>>>(batch, gstart);

    // ---- layer 1 (F_IN -> D) ----
    k_init_z<<<2048, 256, 0, stream>>>(x, z0, eps1, NN * FIN);
    k_edge_scatter<<<NE, 128, 0, stream>>>(x, z0, srcI, dstI, FIN);
    k_gemm_fused<<<gemmGrid, 256, 0, stream>>>(z0, m1w1, m1b1, m1g, m1bb, m1m, m1v,
                                               bufA, NN, FIN, DD, 0);
    k_gemm_fused<<<gemmGrid, 256, 0, stream>>>(bufA, m1w2, m1b2, nullptr, nullptr, nullptr, nullptr,
                                               bufB, NN, DD, DD, 1);
    k_gemm_fused<<<gemmGrid, 256, 0, stream>>>(bufB, o1w, o1b, nullptr, nullptr, nullptr, nullptr,
                                               bufA, NN, DD, DD, 2);   // t1 in bufA

    // ---- layer 2 ----
    k_init_z<<<4096, 256, 0, stream>>>(bufA, bufB, eps2, NN * DD);
    k_edge_scatter<<<NE, 256, 0, stream>>>(bufA, bufB, srcI, dstI, DD);
    k_gemm_fused<<<gemmGrid, 256, 0, stream>>>(bufB, m2w1, m2b1, m2g, m2bb, m2m, m2v,
                                               bufA, NN, DD, DD, 0);
    k_gemm_fused<<<gemmGrid, 256, 0, stream>>>(bufA, m2w2, m2b2, nullptr, nullptr, nullptr, nullptr,
                                               bufB, NN, DD, DD, 1);
    k_gemm_fused<<<gemmGrid, 256, 0, stream>>>(bufB, o2w, o2b, nullptr, nullptr, nullptr, nullptr,
                                               bufA, NN, DD, DD, 2);   // t2 in bufA

    // ---- layer 3 (re-uses mlp2 weights) ----
    k_init_z<<<4096, 256, 0, stream>>>(bufA, bufB, eps3, NN * DD);
    k_edge_scatter<<<NE, 256, 0, stream>>>(bufA, bufB, srcI, dstI, DD);
    k_gemm_fused<<<gemmGrid, 256, 0, stream>>>(bufB, m2w1, m2b1, m2g, m2bb, m2m, m2v,
                                               bufA, NN, DD, DD, 0);
    k_gemm_fused<<<gemmGrid, 256, 0, stream>>>(bufA, m2w2, m2b2, nullptr, nullptr, nullptr, nullptr,
                                               bufB, NN, DD, DD, 1);
    k_gemm_fused<<<gemmGrid, 256, 0, stream>>>(bufB, o3w, o3b, nullptr, nullptr, nullptr, nullptr,
                                               bufA, NN, DD, DD, 2);   // t3 in bufA

    // ---- pooling + readout ----
    k_pool<<<dim3(NG, 4), 128, 0, stream>>>(bufA, gstart, pooled);
    k_final<<<NG, 256, 0, stream>>>(pooled, ow, ob, out);
}

// Round 2
// 1292.366 us; speedup vs baseline: 3.1537x; 3.1537x over previous
//
#include <hip/hip_runtime.h>
#include <math.h>

#define NN 50000
#define NE 400000
#define NG 256
#define FIN 79
#define DD 400
#define LDK 416      // padded K / row stride for D-sized bf16 activations
#define LDK1 96      // padded K for layer-1 z (FIN=79 -> 96)
#define NPAD 448     // padded N for packed weights
#define BN_EPS_F 1e-5f

typedef unsigned short u16;
typedef unsigned short ushort8 __attribute__((ext_vector_type(8)));
typedef unsigned short ushort2v __attribute__((ext_vector_type(2)));
typedef short short8 __attribute__((ext_vector_type(8)));
typedef float floatx4 __attribute__((ext_vector_type(4)));

__device__ inline u16 f2bf(float f) {
    unsigned int u = __builtin_bit_cast(unsigned int, f);
    u += 0x7fffu + ((u >> 16) & 1u);          // round-to-nearest-even
    return (u16)(u >> 16);
}
__device__ inline float bf2f(u16 s) {
    unsigned int u = ((unsigned int)s) << 16;
    return __builtin_bit_cast(float, u);
}

// ---------------- per-graph start offsets via binary search ----------------
__global__ void k_gstart(const int* __restrict__ batch, int* __restrict__ gstart) {
    int g = blockIdx.x * blockDim.x + threadIdx.x;
    if (g > NG) return;
    int lo = 0, hi = NN;
    while (lo < hi) {
        int mid = (lo + hi) >> 1;
        if (batch[mid] < g) lo = mid + 1; else hi = mid;
    }
    gstart[g] = lo;
}

// ---------------- CSR build ----------------
__global__ void k_zero_int(int* __restrict__ p, int n) {
    int i = blockIdx.x * blockDim.x + threadIdx.x;
    if (i < n) p[i] = 0;
}
__global__ void k_hist(const int* __restrict__ dst, int* __restrict__ deg) {
    int e = blockIdx.x * blockDim.x + threadIdx.x;
    if (e < NE) atomicAdd(&deg[dst[e]], 1);
}
__global__ void k_scan(const int* __restrict__ deg, int* __restrict__ rowptr,
                       int* __restrict__ cursor) {
    __shared__ int buf[1024];
    __shared__ int carry_s;
    int t = threadIdx.x;
    if (t == 0) carry_s = 0;
    __syncthreads();
    for (int base = 0; base < NN; base += 1024) {
        int v = (base + t < NN) ? deg[base + t] : 0;
        buf[t] = v;
        __syncthreads();
        for (int off = 1; off < 1024; off <<= 1) {
            int add = (t >= off) ? buf[t - off] : 0;
            __syncthreads();
            buf[t] += add;
            __syncthreads();
        }
        int c = carry_s;
        int excl = c + buf[t] - v;
        if (base + t < NN) { rowptr[base + t] = excl; cursor[base + t] = excl; }
        __syncthreads();
        if (t == 1023) carry_s = c + buf[1023];
        __syncthreads();
    }
    if (t == 0) rowptr[NN] = carry_s;
}
__global__ void k_fill(const int* __restrict__ src, const int* __restrict__ dst,
                       int* __restrict__ cursor, int* __restrict__ eidx) {
    int e = blockIdx.x * blockDim.x + threadIdx.x;
    if (e < NE) {
        int pos = atomicAdd(&cursor[dst[e]], 1);
        eidx[pos] = src[e];
    }
}

// ---------------- weight pack: W[K][400] fp32 -> Wt[NPAD][ldk] bf16 (transposed, zero-padded)
__global__ void k_packw(const float* __restrict__ W, int K, u16* __restrict__ Wt, int ldk) {
    int idx = blockIdx.x * 256 + threadIdx.x;
    int total = NPAD * ldk;
    if (idx >= total) return;
    int n = idx / ldk, k = idx - n * ldk;
    float v = (n < DD && k < K) ? W[(size_t)k * DD + n] : 0.0f;
    Wt[idx] = f2bf(v);
}

// ---------------- layer-1 aggregation: z0 = (1+eps)*x + sum_{src->n} x[src]  (fp32 in, bf16 out)
__global__ __launch_bounds__(128)
void k_agg1(const float* __restrict__ x, const int* __restrict__ rowptr,
            const int* __restrict__ eidx, const float* __restrict__ eps,
            u16* __restrict__ z0) {
    int n = blockIdx.x;
    int t = threadIdx.x;
    float acc = 0.0f;
    if (t < FIN) acc = (1.0f + eps[0]) * x[(size_t)n * FIN + t];
    int e0 = rowptr[n], e1 = rowptr[n + 1];
    for (int i = e0; i < e1; ++i) {
        int s = eidx[i];
        if (t < FIN) acc += x[(size_t)s * FIN + t];
    }
    if (t < LDK1) z0[(size_t)n * LDK1 + t] = (t < FIN) ? f2bf(acc) : (u16)0;
}

// ---------------- D aggregation: z = (1+eps)*h + sum h[src]  (bf16 in/out, fp32 accum)
__global__ __launch_bounds__(256)
void k_agg(const u16* __restrict__ h, const int* __restrict__ rowptr,
           const int* __restrict__ eidx, const float* __restrict__ eps,
           u16* __restrict__ z) {
    int n = blockIdx.x;
    int t = threadIdx.x;          // t<200 handles cols 2t, 2t+1
    float s = 1.0f + eps[0];
    float a0 = 0.0f, a1 = 0.0f;
    const u16* hr = h + (size_t)n * LDK;
    if (t < 200) {
        ushort2v v = *(const ushort2v*)&hr[2 * t];
        a0 = s * bf2f(v.x); a1 = s * bf2f(v.y);
    }
    int e0 = rowptr[n], e1 = rowptr[n + 1];
    for (int i = e0; i < e1; ++i) {
        int src = eidx[i];
        const u16* hs = h + (size_t)src * LDK;
        if (t < 200) {
            ushort2v v = *(const ushort2v*)&hs[2 * t];
            a0 += bf2f(v.x); a1 += bf2f(v.y);
        }
    }
    u16* zr = z + (size_t)n * LDK;
    if (t < 200) {
        zr[2 * t] = f2bf(a0); zr[2 * t + 1] = f2bf(a1);
    } else if (t < 208) {
        zr[2 * t] = 0; zr[2 * t + 1] = 0;
    }
}

// ---------------- bf16 MFMA GEMM: Y = epilogue(A @ Wt^T + bias) ----------------
// A: [NN][lda] bf16 row-major (K padded, zeros), Wt: [NPAD][lda] bf16 (= W^T padded)
// Y: [NN][LDK] bf16, cols [DD,LDK) zeroed. mode 0: BN+relu, 1: relu, 2: tanh
__global__ __launch_bounds__(256)
void k_gemm(const u16* __restrict__ A, int lda, int ktiles,
            const u16* __restrict__ Wt,
            const float* __restrict__ bias,
            const float* __restrict__ bng, const float* __restrict__ bnb,
            const float* __restrict__ bnm, const float* __restrict__ bnv,
            u16* __restrict__ Y, int mode)
{
    __shared__ u16 As[128][40];   // 32 cols + 8 pad
    __shared__ u16 Bs[64][40];

    int tid = threadIdx.x;
    int wave = tid >> 6, lane = tid & 63;
    int wr = wave & 1, wc = wave >> 1;     // wave grid 2x2 over (M:2x64, N:2x32)
    int m0 = blockIdx.x * 128;
    int n0 = blockIdx.y * 64;

    int rA = tid >> 2;                     // 0..63
    int cA = (tid & 3) * 8;
    int lqk = (lane >> 4) * 8;             // k-offset of this lane's fragment
    int lm = lane & 15;

    floatx4 acc[4][2] = {};

    for (int kt = 0; kt < ktiles; ++kt) {
        int k0 = kt * 32;
        {
            int gr = m0 + rA;
            ushort8 v = {0, 0, 0, 0, 0, 0, 0, 0};
            if (gr < NN) v = *(const ushort8*)&A[(size_t)gr * lda + k0 + cA];
            *(ushort8*)&As[rA][cA] = v;
            gr = m0 + rA + 64;
            ushort8 w = {0, 0, 0, 0, 0, 0, 0, 0};
            if (gr < NN) w = *(const ushort8*)&A[(size_t)gr * lda + k0 + cA];
            *(ushort8*)&As[rA + 64][cA] = w;
            ushort8 b = *(const ushort8*)&Wt[(size_t)(n0 + rA) * lda + k0 + cA];
            *(ushort8*)&Bs[rA][cA] = b;
        }
        __syncthreads();
        short8 af[4], bfr[2];
        #pragma unroll
        for (int i = 0; i < 4; ++i)
            af[i] = *(const short8*)&As[wr * 64 + i * 16 + lm][lqk];
        #pragma unroll
        for (int j = 0; j < 2; ++j)
            bfr[j] = *(const short8*)&Bs[wc * 32 + j * 16 + lm][lqk];
        #pragma unroll
        for (int i = 0; i < 4; ++i)
            #pragma unroll
            for (int j = 0; j < 2; ++j)
                acc[i][j] = __builtin_amdgcn_mfma_f32_16x16x32_bf16(af[i], bfr[j], acc[i][j], 0, 0, 0);
        __syncthreads();
    }

    int lr = (lane >> 4) * 4;
    int lc = lane & 15;
    #pragma unroll
    for (int i = 0; i < 4; ++i) {
        #pragma unroll
        for (int j = 0; j < 2; ++j) {
            #pragma unroll
            for (int r = 0; r < 4; ++r) {
                int m = m0 + wr * 64 + i * 16 + lr + r;
                int n = n0 + wc * 32 + j * 16 + lc;
                if (m < NN && n < LDK) {
                    if (n < DD) {
                        float val = acc[i][j][r] + bias[n];
                        if (mode == 0) {
                            float sc = bng[n] * rsqrtf(bnv[n] + BN_EPS_F);
                            float sh = bnb[n] - bnm[n] * sc;
                            val = fmaxf(fmaf(val, sc, sh), 0.0f);
                        } else if (mode == 1) {
                            val = fmaxf(val, 0.0f);
                        } else {
                            val = tanhf(val);
                        }
                        Y[(size_t)m * LDK + n] = f2bf(val);
                    } else {
                        Y[(size_t)m * LDK + n] = 0;
                    }
                }
            }
        }
    }
}

// ---------------- pooling: max + mean per graph (bf16 in, fp32 out) ----------------
__global__ void k_pool(const u16* __restrict__ t3, const int* __restrict__ gstart,
                       float* __restrict__ pooled) {
    int g = blockIdx.x;
    int c = blockIdx.y * 128 + threadIdx.x;
    if (c >= DD) return;
    int s = gstart[g], e = gstart[g + 1];
    float mx = -INFINITY, sm = 0.0f;
    for (int n = s; n < e; ++n) {
        float v = bf2f(t3[(size_t)n * LDK + c]);
        mx = fmaxf(mx, v);
        sm += v;
    }
    float cnt = (float)(e - s);
    pooled[(size_t)g * 2 * DD + c] = mx;
    pooled[(size_t)g * 2 * DD + DD + c] = sm / fmaxf(cnt, 1.0f);
}

// ---------------- final readout ----------------
__global__ void k_final(const float* __restrict__ pooled, const float* __restrict__ w,
                        const float* __restrict__ b, float* __restrict__ out) {
    __shared__ float red[256];
    int g = blockIdx.x;
    float p = 0.0f;
    for (int j = threadIdx.x; j < 2 * DD; j += blockDim.x)
        p += pooled[(size_t)g * 2 * DD + j] * w[j];
    red[threadIdx.x] = p;
    __syncthreads();
    for (int s = 128; s > 0; s >>= 1) {
        if (threadIdx.x < s) red[threadIdx.x] += red[threadIdx.x + s];
        __syncthreads();
    }
    if (threadIdx.x == 0) out[g] = red[0] + b[0];
}

extern "C" void kernel_launch(void* const* d_in, const int* in_sizes, int n_in,
                              void* d_out, int out_size, void* d_ws, size_t ws_size,
                              hipStream_t stream) {
    const float* x     = (const float*)d_in[0];
    const int*   ei    = (const int*)d_in[1];
    const int*   batch = (const int*)d_in[2];
    const float* m1w1  = (const float*)d_in[4];
    const float* m1b1  = (const float*)d_in[5];
    const float* m1g   = (const float*)d_in[6];
    const float* m1bb  = (const float*)d_in[7];
    const float* m1m   = (const float*)d_in[8];
    const float* m1v   = (const float*)d_in[9];
    const float* m1w2  = (const float*)d_in[10];
    const float* m1b2  = (const float*)d_in[11];
    const float* m2w1  = (const float*)d_in[12];
    const float* m2b1  = (const float*)d_in[13];
    const float* m2g   = (const float*)d_in[14];
    const float* m2bb  = (const float*)d_in[15];
    const float* m2m   = (const float*)d_in[16];
    const float* m2v   = (const float*)d_in[17];
    const float* m2w2  = (const float*)d_in[18];
    const float* m2b2  = (const float*)d_in[19];
    const float* o1w   = (const float*)d_in[20];
    const float* o1b   = (const float*)d_in[21];
    const float* o2w   = (const float*)d_in[22];
    const float* o2b   = (const float*)d_in[23];
    const float* o3w   = (const float*)d_in[24];
    const float* o3b   = (const float*)d_in[25];
    const float* ow    = (const float*)d_in[26];
    const float* ob    = (const float*)d_in[27];
    const float* eps1  = (const float*)d_in[28];
    const float* eps2  = (const float*)d_in[29];
    const float* eps3  = (const float*)d_in[30];
    const int* srcI = ei;
    const int* dstI = ei + NE;

    // ---- workspace layout (all 16B-aligned chunks) ----
    u16* buf1 = (u16*)d_ws;                          // NN*LDK
    u16* buf2 = buf1 + (size_t)NN * LDK;
    u16* buf3 = buf2 + (size_t)NN * LDK;
    u16* z0   = buf3 + (size_t)NN * LDK;             // NN*LDK1
    u16* w1t  = z0 + (size_t)NN * LDK1;              // NPAD*LDK1
    u16* m1w2t = w1t + (size_t)NPAD * LDK1;          // NPAD*LDK each
    u16* m2w1t = m1w2t + (size_t)NPAD * LDK;
    u16* m2w2t = m2w1t + (size_t)NPAD * LDK;
    u16* o1t   = m2w2t + (size_t)NPAD * LDK;
    u16* o2t   = o1t + (size_t)NPAD * LDK;
    u16* o3t   = o2t + (size_t)NPAD * LDK;
    float* pooled = (float*)(o3t + (size_t)NPAD * LDK);   // NG*2*DD
    int* gstart = (int*)(pooled + (size_t)NG * 2 * DD);   // NG+1
    int* rowptr = gstart + (NG + 2);                      // NN+1
    int* cursor = rowptr + (NN + 1);                      // NN
    int* deg    = cursor + NN;                            // NN
    int* eidx   = deg + NN;                               // NE

    float* out = (float*)d_out;

    dim3 gemmGrid((NN + 127) / 128, (NPAD + 63) / 64);

    // graph structure (same every call)
    k_gstart<<<2, 256, 0, stream>>>(batch, gstart);
    k_zero_int<<<(NN + 255) / 256, 256, 0, stream>>>(deg, NN);
    k_hist<<<(NE + 255) / 256, 256, 0, stream>>>(dstI, deg);
    k_scan<<<1, 1024, 0, stream>>>(deg, rowptr, cursor);
    k_fill<<<(NE + 255) / 256, 256, 0, stream>>>(srcI, dstI, cursor, eidx);

    // pack weights to bf16 transposed
    int pw1 = (NPAD * LDK1 + 255) / 256;
    int pw = (NPAD * LDK + 255) / 256;
    k_packw<<<pw1, 256, 0, stream>>>(m1w1, FIN, w1t, LDK1);
    k_packw<<<pw, 256, 0, stream>>>(m1w2, DD, m1w2t, LDK);
    k_packw<<<pw, 256, 0, stream>>>(m2w1, DD, m2w1t, LDK);
    k_packw<<<pw, 256, 0, stream>>>(m2w2, DD, m2w2t, LDK);
    k_packw<<<pw, 256, 0, stream>>>(o1w, DD, o1t, LDK);
    k_packw<<<pw, 256, 0, stream>>>(o2w, DD, o2t, LDK);
    k_packw<<<pw, 256, 0, stream>>>(o3w, DD, o3t, LDK);

    // ---- layer 1 ----
    k_agg1<<<NN, 128, 0, stream>>>(x, rowptr, eidx, eps1, z0);
    k_gemm<<<gemmGrid, 256, 0, stream>>>(z0, LDK1, LDK1 / 32, w1t, m1b1,
                                         m1g, m1bb, m1m, m1v, buf1, 0);
    k_gemm<<<gemmGrid, 256, 0, stream>>>(buf1, LDK, LDK / 32, m1w2t, m1b2,
                                         nullptr, nullptr, nullptr, nullptr, buf2, 1);
    k_gemm<<<gemmGrid, 256, 0, stream>>>(buf2, LDK, LDK / 32, o1t, o1b,
                                         nullptr, nullptr, nullptr, nullptr, buf3, 2);  // t1 = buf3

    // ---- layer 2 ----
    k_agg<<<NN, 256, 0, stream>>>(buf3, rowptr, eidx, eps2, buf1);
    k_gemm<<<gemmGrid, 256, 0, stream>>>(buf1, LDK, LDK / 32, m2w1t, m2b1,
                                         m2g, m2bb, m2m, m2v, buf2, 0);
    k_gemm<<<gemmGrid, 256, 0, stream>>>(buf2, LDK, LDK / 32, m2w2t, m2b2,
                                         nullptr, nullptr, nullptr, nullptr, buf1, 1);
    k_gemm<<<gemmGrid, 256, 0, stream>>>(buf1, LDK, LDK / 32, o2t, o2b,
                                         nullptr, nullptr, nullptr, nullptr, buf2, 2);  // t2 = buf2

    // ---- layer 3 (mlp2 weights again) ----
    k_agg<<<NN, 256, 0, stream>>>(buf2, rowptr, eidx, eps3, buf1);
    k_gemm<<<gemmGrid, 256, 0, stream>>>(buf1, LDK, LDK / 32, m2w1t, m2b1,
                                         m2g, m2bb, m2m, m2v, buf3, 0);
    k_gemm<<<gemmGrid, 256, 0, stream>>>(buf3, LDK, LDK / 32, m2w2t, m2b2,
                                         nullptr, nullptr, nullptr, nullptr, buf1, 1);
    k_gemm<<<gemmGrid, 256, 0, stream>>>(buf1, LDK, LDK / 32, o3t, o3b,
                                         nullptr, nullptr, nullptr, nullptr, buf3, 2);  // t3 = buf3

    // ---- pooling + readout ----
    k_pool<<<dim3(NG, 4), 128, 0, stream>>>(buf3, gstart, pooled);
    k_final<<<NG, 256, 0, stream>>>(pooled, ow, ob, out);
}